// Round 1
// baseline (760.182 us; speedup 1.0000x reference)
//
#include <hip/hip_runtime.h>
#include <math.h>

#define BB 4
#define TT 1024
#define DM 1024
#define NH 16
#define HD 64
#define DFF 4096
#define N3 3072

typedef unsigned short u16;
typedef __attribute__((ext_vector_type(4))) float f32x4;
typedef __attribute__((ext_vector_type(8))) short s16x8;

__device__ __forceinline__ u16 f2bf(float f) {
    union { float f; unsigned u; } v; v.f = f;
    unsigned u = v.u;
    u += 0x7fffu + ((u >> 16) & 1u);
    return (u16)(u >> 16);
}
__device__ __forceinline__ float bf2f(u16 h) {
    union { unsigned u; float f; } v; v.u = ((unsigned)h) << 16;
    return v.f;
}

__device__ __forceinline__ void async_copy16(const void* g, void* l) {
    __builtin_amdgcn_global_load_lds(
        (const __attribute__((address_space(1))) unsigned int*)g,
        (__attribute__((address_space(3))) unsigned int*)l, 16, 0, 0);
}

// ---------------- convert fp32 -> bf16 ----------------
__global__ __launch_bounds__(256) void cvt_kernel(const float* __restrict__ in,
                                                  u16* __restrict__ out, int n) {
    int i = (blockIdx.x * 256 + threadIdx.x) * 4;
    if (i + 3 < n) {
        out[i + 0] = f2bf(in[i + 0]);
        out[i + 1] = f2bf(in[i + 1]);
        out[i + 2] = f2bf(in[i + 2]);
        out[i + 3] = f2bf(in[i + 3]);
    }
}

// ---------------- tiled transpose + convert: out[c][r] = in[r][c] ----------------
// TIN: 0 = float input, 1 = bf16(u16) input. grid = (C/32, R/32, batch)
template<int TIN>
__global__ __launch_bounds__(256) void transpose_kernel(const void* __restrict__ inv,
                                                        u16* __restrict__ out, int R, int C) {
    __shared__ float tile[32][33];
    const float* inF = (const float*)inv;
    const u16* inH = (const u16*)inv;
    size_t boff = (size_t)blockIdx.z * R * C;
    int c0 = blockIdx.x * 32, r0 = blockIdx.y * 32;
    int tx = threadIdx.x & 31, ty = threadIdx.x >> 5;  // ty: 0..7
    for (int i = 0; i < 4; i++) {
        int r = r0 + ty + i * 8, c = c0 + tx;
        float v = (TIN == 0) ? inF[boff + (size_t)r * C + c] : bf2f(inH[boff + (size_t)r * C + c]);
        tile[ty + i * 8][tx] = v;
    }
    __syncthreads();
    for (int i = 0; i < 4; i++) {
        int rr = r0 + tx, cc = c0 + ty + i * 8;
        out[boff + (size_t)cc * R + rr] = f2bf(tile[tx][ty + i * 8]);
    }
}

// ---------------- bf16 MFMA GEMM: C = A[M][K] @ BT[N][K]^T + bias ----------------
// EPI: 0 = bf16 store to out0[M][N]; 1 = qkv head-major scatter (out0=Q,out1=K,out2=V);
//      2 = exact gelu then bf16 store to out0.
template<int EPI>
__global__ __launch_bounds__(256) void gemm_kernel(const u16* __restrict__ A,
                                                   const u16* __restrict__ BT,
                                                   const float* __restrict__ bias,
                                                   u16* __restrict__ out0, u16* __restrict__ out1,
                                                   u16* __restrict__ out2, int M, int N, int K) {
    __shared__ u16 As[128 * 32];
    __shared__ u16 Bs[128 * 32];
    const int tid = threadIdx.x;
    const int lane = tid & 63;
    const int wave = tid >> 6;
    const int quad = lane >> 4;
    const int l15 = lane & 15;
    const int wy = wave >> 1, wx = wave & 1;
    const int m0 = blockIdx.y * 128;
    const int n0 = blockIdx.x * 128;

    const int ai0 = wave * 2, ai1 = wave * 2 + 1;
    const u16* aG0 = A + (size_t)(m0 + ai0 * 16 + (lane >> 2)) * K + (lane & 3) * 8;
    const u16* aG1 = A + (size_t)(m0 + ai1 * 16 + (lane >> 2)) * K + (lane & 3) * 8;
    const u16* bG0 = BT + (size_t)(n0 + ai0 * 16 + (lane >> 2)) * K + (lane & 3) * 8;
    const u16* bG1 = BT + (size_t)(n0 + ai1 * 16 + (lane >> 2)) * K + (lane & 3) * 8;
    u16* aL0 = &As[ai0 * 512];
    u16* aL1 = &As[ai1 * 512];
    u16* bL0 = &Bs[ai0 * 512];
    u16* bL1 = &Bs[ai1 * 512];

    f32x4 acc[4][4] = {};

    for (int k0 = 0; k0 < K; k0 += 32) {
        async_copy16(aG0 + k0, aL0);
        async_copy16(aG1 + k0, aL1);
        async_copy16(bG0 + k0, bL0);
        async_copy16(bG1 + k0, bL1);
        __syncthreads();
        s16x8 af[4], bf[4];
#pragma unroll
        for (int i = 0; i < 4; i++)
            af[i] = *(const s16x8*)&As[(wy * 64 + i * 16 + l15) * 32 + quad * 8];
#pragma unroll
        for (int j = 0; j < 4; j++)
            bf[j] = *(const s16x8*)&Bs[(wx * 64 + j * 16 + l15) * 32 + quad * 8];
#pragma unroll
        for (int i = 0; i < 4; i++)
#pragma unroll
            for (int j = 0; j < 4; j++)
                acc[i][j] = __builtin_amdgcn_mfma_f32_16x16x32_bf16(af[i], bf[j], acc[i][j], 0, 0, 0);
        __syncthreads();
    }

#pragma unroll
    for (int i = 0; i < 4; i++) {
#pragma unroll
        for (int j = 0; j < 4; j++) {
            f32x4 c = acc[i][j];
            int gn = n0 + wx * 64 + j * 16 + l15;
            float bv = bias[gn];
#pragma unroll
            for (int r = 0; r < 4; r++) {
                int gm = m0 + wy * 64 + i * 16 + quad * 4 + r;
                float v = c[r] + bv;
                if (EPI == 2) v = 0.5f * v * (1.f + erff(v * 0.70710678118f));
                if (EPI == 0 || EPI == 2) {
                    out0[(size_t)gm * N + gn] = f2bf(v);
                } else {
                    int which = gn >> 10, h = (gn >> 6) & 15, d = gn & 63;
                    int bb = gm >> 10, t = gm & 1023;
                    u16* dst = (which == 0) ? out0 : ((which == 1) ? out1 : out2);
                    dst[((size_t)(bb * NH + h) * TT + t) * HD + d] = f2bf(v);
                }
            }
        }
    }
}

// ---------------- attention: per block = (b, h, 16 q rows) ----------------
__global__ __launch_bounds__(256) void attn_kernel(const u16* __restrict__ Qb,
                                                   const u16* __restrict__ Kb,
                                                   const u16* __restrict__ VTb,
                                                   const float* __restrict__ rel_bias,
                                                   const float* __restrict__ temp_p,
                                                   float* __restrict__ probs_out,
                                                   u16* __restrict__ attn_out) {
    __shared__ u16 Qs[16 * 72];
    __shared__ u16 Ps[16 * 1032];
    __shared__ float red[2][4][16];
    __shared__ float Op[4][16][64];

    const int tid = threadIdx.x;
    const int lane = tid & 63, wave = tid >> 6, quad = lane >> 4, l15 = lane & 15;
    const int q0 = blockIdx.x * 16;
    const int h = blockIdx.y, b = blockIdx.z;
    const int bh = b * NH + h;
    const size_t headoff = (size_t)bh * TT * HD;

    float temp = fmaxf(temp_p[0], 0.01f);
    const float itemp = 1.f / temp;

    {  // load 16x64 Q tile into LDS (padded rows of 72)
        int row = tid >> 4, col = (tid & 15) * 4;
        const u16* srcp = Qb + headoff + (size_t)(q0 + row) * HD + col;
        *(uint2*)&Qs[row * 72 + col] = *(const uint2*)srcp;
    }
    __syncthreads();

    // ---- S = Q K^T * (1/temp) + rel_bias ----
    s16x8 a0 = *(const s16x8*)&Qs[l15 * 72 + quad * 8];
    s16x8 a1 = *(const s16x8*)&Qs[l15 * 72 + 32 + quad * 8];
    f32x4 s[16];
    const u16* Kh = Kb + headoff;
#pragma unroll
    for (int nt = 0; nt < 16; nt++) {
        int key = wave * 256 + nt * 16 + l15;
        const u16* kp = Kh + (size_t)key * HD;
        s16x8 b0 = *(const s16x8*)(kp + quad * 8);
        s16x8 b1 = *(const s16x8*)(kp + 32 + quad * 8);
        f32x4 acc = {};
        acc = __builtin_amdgcn_mfma_f32_16x16x32_bf16(a0, b0, acc, 0, 0, 0);
        acc = __builtin_amdgcn_mfma_f32_16x16x32_bf16(a1, b1, acc, 0, 0, 0);
#pragma unroll
        for (int r = 0; r < 4; r++) {
            int q = q0 + quad * 4 + r;
            acc[r] = acc[r] * itemp + rel_bias[h * 2047 + (key - q + 1023)];
        }
        s[nt] = acc;
    }

    // ---- row max (16-lane shuffle + cross-wave LDS) ----
    float lm[4];
#pragma unroll
    for (int r = 0; r < 4; r++) {
        float m = s[0][r];
#pragma unroll
        for (int nt = 1; nt < 16; nt++) m = fmaxf(m, s[nt][r]);
        for (int off = 8; off >= 1; off >>= 1) m = fmaxf(m, __shfl_xor(m, off));
        lm[r] = m;
    }
    if (l15 == 0)
        for (int r = 0; r < 4; r++) red[0][wave][quad * 4 + r] = lm[r];
    __syncthreads();
    float rm[4];
#pragma unroll
    for (int r = 0; r < 4; r++) {
        int row = quad * 4 + r;
        rm[r] = fmaxf(fmaxf(red[0][0][row], red[0][1][row]),
                      fmaxf(red[0][2][row], red[0][3][row]));
    }

    // ---- exp + row sum ----
    float ls[4] = {0.f, 0.f, 0.f, 0.f};
#pragma unroll
    for (int nt = 0; nt < 16; nt++)
#pragma unroll
        for (int r = 0; r < 4; r++) {
            float p = __expf(s[nt][r] - rm[r]);
            s[nt][r] = p;
            ls[r] += p;
        }
#pragma unroll
    for (int r = 0; r < 4; r++) {
        float v = ls[r];
        for (int off = 8; off >= 1; off >>= 1) v += __shfl_xor(v, off);
        ls[r] = v;
    }
    if (l15 == 0)
        for (int r = 0; r < 4; r++) red[1][wave][quad * 4 + r] = ls[r];
    __syncthreads();
    float inv[4];
#pragma unroll
    for (int r = 0; r < 4; r++) {
        int row = quad * 4 + r;
        inv[r] = 1.f / (red[1][0][row] + red[1][1][row] + red[1][2][row] + red[1][3][row]);
    }

    // ---- write normalized probs to d_out; stash unnormalized bf16 P in LDS ----
    float* prow = probs_out + ((size_t)bh * TT + q0) * TT;
#pragma unroll
    for (int nt = 0; nt < 16; nt++) {
        int key = wave * 256 + nt * 16 + l15;
#pragma unroll
        for (int r = 0; r < 4; r++) {
            int row = quad * 4 + r;
            prow[(size_t)row * TT + key] = s[nt][r] * inv[r];
            Ps[row * 1032 + key] = f2bf(s[nt][r]);
        }
    }
    __syncthreads();

    // ---- O = P V (each wave owns a 256-key slab, partials summed in LDS) ----
    f32x4 o[4] = {};
    const u16* Vh = VTb + headoff;
#pragma unroll
    for (int ks = 0; ks < 8; ks++) {
        int k0 = wave * 256 + ks * 32;
        s16x8 pa = *(const s16x8*)&Ps[l15 * 1032 + k0 + quad * 8];
#pragma unroll
        for (int nt = 0; nt < 4; nt++) {
            int d = nt * 16 + l15;
            s16x8 vb = *(const s16x8*)(Vh + (size_t)d * TT + k0 + quad * 8);
            o[nt] = __builtin_amdgcn_mfma_f32_16x16x32_bf16(pa, vb, o[nt], 0, 0, 0);
        }
    }
#pragma unroll
    for (int nt = 0; nt < 4; nt++)
#pragma unroll
        for (int r = 0; r < 4; r++) Op[wave][quad * 4 + r][nt * 16 + l15] = o[nt][r];
    __syncthreads();

    {
        int m = tid >> 4, dc = (tid & 15) * 4;
        float acc4[4];
#pragma unroll
        for (int c = 0; c < 4; c++)
            acc4[c] = Op[0][m][dc + c] + Op[1][m][dc + c] + Op[2][m][dc + c] + Op[3][m][dc + c];
        float rinv = 1.f / (red[1][0][m] + red[1][1][m] + red[1][2][m] + red[1][3][m]);
        u16 pk[4];
#pragma unroll
        for (int c = 0; c < 4; c++) pk[c] = f2bf(acc4[c] * rinv);
        *(uint2*)&attn_out[((size_t)(b * TT + q0 + m)) * DM + h * HD + dc] = *(uint2*)pk;
    }
}

// ---------------- layernorm ----------------
// MODE 0: x = LN(src_f32 + add_bf) -> out bf16     (LN1)
// MODE 1: y = LN(a_bf + scale*add_bf) -> out fp32  (LN2)
template<int MODE>
__global__ __launch_bounds__(256) void ln_kernel(const float* __restrict__ af32,
                                                 const u16* __restrict__ abf,
                                                 const u16* __restrict__ addbf,
                                                 const float* __restrict__ scale_p,
                                                 const float* __restrict__ gamma,
                                                 const float* __restrict__ beta,
                                                 float* __restrict__ outf,
                                                 u16* __restrict__ outbf) {
    __shared__ float red[2][4];
    int row = blockIdx.x;
    int tid = threadIdx.x;
    float scale = (MODE == 1) ? scale_p[0] : 1.f;
    int c0 = tid * 4;
    size_t base = (size_t)row * DM + c0;
    float x[4];
#pragma unroll
    for (int c = 0; c < 4; c++) {
        float v = (MODE == 0) ? af32[base + c] : bf2f(abf[base + c]);
        v += scale * bf2f(addbf[base + c]);
        x[c] = v;
    }
    float s = x[0] + x[1] + x[2] + x[3];
    float sq = x[0] * x[0] + x[1] * x[1] + x[2] * x[2] + x[3] * x[3];
    for (int off = 32; off >= 1; off >>= 1) {
        s += __shfl_xor(s, off);
        sq += __shfl_xor(sq, off);
    }
    int wave = tid >> 6;
    if ((tid & 63) == 0) {
        red[0][wave] = s;
        red[1][wave] = sq;
    }
    __syncthreads();
    s = red[0][0] + red[0][1] + red[0][2] + red[0][3];
    sq = red[1][0] + red[1][1] + red[1][2] + red[1][3];
    float mu = s * (1.f / DM);
    float var = sq * (1.f / DM) - mu * mu;
    float rs = rsqrtf(var + 1e-5f);
#pragma unroll
    for (int c = 0; c < 4; c++) {
        float y = (x[c] - mu) * rs * gamma[c0 + c] + beta[c0 + c];
        if (MODE == 0) outbf[base + c] = f2bf(y);
        else outf[base + c] = y;
    }
}

// ---------------- workspace layout (bytes) ----------------
#define OFF_SRCBF 0UL
#define OFF_WQKVT 8388608UL
#define OFF_WOT 14680064UL
#define OFF_W1T 16777216UL
#define OFF_W2T 25165824UL
#define OFF_Q 33554432UL
#define OFF_K 41943040UL
#define OFF_V 50331648UL
#define OFF_VT 58720256UL
#define OFF_ATTNO 67108864UL
#define OFF_PROJ 75497472UL
#define OFF_XBF 83886080UL
#define OFF_H1 92274688UL

extern "C" void kernel_launch(void* const* d_in, const int* in_sizes, int n_in,
                              void* d_out, int out_size, void* d_ws, size_t ws_size,
                              hipStream_t stream) {
    const float* src = (const float*)d_in[0];
    const float* Wqkv = (const float*)d_in[1];
    const float* bqkv = (const float*)d_in[2];
    const float* Wo = (const float*)d_in[3];
    const float* bo = (const float*)d_in[4];
    const float* relb = (const float*)d_in[5];
    const float* temp = (const float*)d_in[6];
    const float* W1 = (const float*)d_in[7];
    const float* b1 = (const float*)d_in[8];
    const float* W2 = (const float*)d_in[9];
    const float* b2 = (const float*)d_in[10];
    const float* ffs = (const float*)d_in[11];
    const float* g1 = (const float*)d_in[12];
    const float* be1 = (const float*)d_in[13];
    const float* g2 = (const float*)d_in[14];
    const float* be2 = (const float*)d_in[15];

    char* ws = (char*)d_ws;
    u16* srcbf = (u16*)(ws + OFF_SRCBF);
    u16* WqkvT = (u16*)(ws + OFF_WQKVT);
    u16* WoT = (u16*)(ws + OFF_WOT);
    u16* W1T = (u16*)(ws + OFF_W1T);
    u16* W2T = (u16*)(ws + OFF_W2T);
    u16* Qb = (u16*)(ws + OFF_Q);
    u16* Kb = (u16*)(ws + OFF_K);
    u16* Vb = (u16*)(ws + OFF_V);
    u16* VTb = (u16*)(ws + OFF_VT);
    u16* attnbf = (u16*)(ws + OFF_ATTNO);
    u16* projbf = (u16*)(ws + OFF_PROJ);
    u16* xbf = (u16*)(ws + OFF_XBF);
    u16* h1bf = (u16*)(ws + OFF_H1);

    float* out_f = (float*)d_out;
    float* probs = out_f + (size_t)BB * TT * DM;

    // 1. src -> bf16
    cvt_kernel<<<4096, 256, 0, stream>>>(src, srcbf, BB * TT * DM);
    // 2-5. weight transposes (fp32 [K][N] -> bf16 [N][K])
    transpose_kernel<0><<<dim3(N3 / 32, DM / 32, 1), 256, 0, stream>>>(Wqkv, WqkvT, DM, N3);
    transpose_kernel<0><<<dim3(DM / 32, DM / 32, 1), 256, 0, stream>>>(Wo, WoT, DM, DM);
    transpose_kernel<0><<<dim3(DFF / 32, DM / 32, 1), 256, 0, stream>>>(W1, W1T, DM, DFF);
    transpose_kernel<0><<<dim3(DM / 32, DFF / 32, 1), 256, 0, stream>>>(W2, W2T, DFF, DM);
    // 6. QKV GEMM with head-major scatter
    gemm_kernel<1><<<dim3(N3 / 128, (BB * TT) / 128), 256, 0, stream>>>(
        srcbf, WqkvT, bqkv, Qb, Kb, Vb, BB * TT, N3, DM);
    // 7. V -> V^T per head
    transpose_kernel<1><<<dim3(HD / 32, TT / 32, BB * NH), 256, 0, stream>>>(Vb, VTb, TT, HD);
    // 8. attention (writes probs to d_out + attn_out bf16)
    attn_kernel<<<dim3(TT / 16, NH, BB), 256, 0, stream>>>(Qb, Kb, VTb, relb, temp, probs, attnbf);
    // 9. output projection
    gemm_kernel<0><<<dim3(DM / 128, (BB * TT) / 128), 256, 0, stream>>>(
        attnbf, WoT, bo, projbf, nullptr, nullptr, BB * TT, DM, DM);
    // 10. LN1: x = LN(src + proj)
    ln_kernel<0><<<BB * TT, 256, 0, stream>>>(src, nullptr, projbf, nullptr, g1, be1, nullptr, xbf);
    // 11. FF1 + exact gelu
    gemm_kernel<2><<<dim3(DFF / 128, (BB * TT) / 128), 256, 0, stream>>>(
        xbf, W1T, b1, h1bf, nullptr, nullptr, BB * TT, DFF, DM);
    // 12. FF2 (reuse proj buffer for ff)
    gemm_kernel<0><<<dim3(DM / 128, (BB * TT) / 128), 256, 0, stream>>>(
        h1bf, W2T, b2, projbf, nullptr, nullptr, BB * TT, DM, DFF);
    // 13. LN2 -> d_out
    ln_kernel<1><<<BB * TT, 256, 0, stream>>>(nullptr, xbf, projbf, ffs, g2, be2, out_f, nullptr);
}

// Round 2
// 704.112 us; speedup vs baseline: 1.0796x; 1.0796x over previous
//
#include <hip/hip_runtime.h>
#include <math.h>

#define BB 4
#define TT 1024
#define DM 1024
#define NH 16
#define HD 64
#define DFF 4096
#define N3 3072

typedef unsigned short u16;
typedef __attribute__((ext_vector_type(4))) float f32x4;
typedef __attribute__((ext_vector_type(8))) short s16x8;

__device__ __forceinline__ u16 f2bf(float f) {
    union { float f; unsigned u; } v; v.f = f;
    unsigned u = v.u;
    u += 0x7fffu + ((u >> 16) & 1u);
    return (u16)(u >> 16);
}
__device__ __forceinline__ float bf2f(u16 h) {
    union { unsigned u; float f; } v; v.u = ((unsigned)h) << 16;
    return v.f;
}

__device__ __forceinline__ void async_copy16(const void* g, void* l) {
    __builtin_amdgcn_global_load_lds(
        (const __attribute__((address_space(1))) unsigned int*)g,
        (__attribute__((address_space(3))) unsigned int*)l, 16, 0, 0);
}

// ---------------- convert fp32 -> bf16 ----------------
__global__ __launch_bounds__(256) void cvt_kernel(const float* __restrict__ in,
                                                  u16* __restrict__ out, int n) {
    int i = (blockIdx.x * 256 + threadIdx.x) * 4;
    if (i + 3 < n) {
        out[i + 0] = f2bf(in[i + 0]);
        out[i + 1] = f2bf(in[i + 1]);
        out[i + 2] = f2bf(in[i + 2]);
        out[i + 3] = f2bf(in[i + 3]);
    }
}

// ---------------- tiled transpose + convert: out[c][r] = in[r][c] ----------------
template<int TIN>
__global__ __launch_bounds__(256) void transpose_kernel(const void* __restrict__ inv,
                                                        u16* __restrict__ out, int R, int C) {
    __shared__ float tile[32][33];
    const float* inF = (const float*)inv;
    const u16* inH = (const u16*)inv;
    size_t boff = (size_t)blockIdx.z * R * C;
    int c0 = blockIdx.x * 32, r0 = blockIdx.y * 32;
    int tx = threadIdx.x & 31, ty = threadIdx.x >> 5;
    for (int i = 0; i < 4; i++) {
        int r = r0 + ty + i * 8, c = c0 + tx;
        float v = (TIN == 0) ? inF[boff + (size_t)r * C + c] : bf2f(inH[boff + (size_t)r * C + c]);
        tile[ty + i * 8][tx] = v;
    }
    __syncthreads();
    for (int i = 0; i < 4; i++) {
        int rr = r0 + tx, cc = c0 + ty + i * 8;
        out[boff + (size_t)cc * R + rr] = f2bf(tile[tx][ty + i * 8]);
    }
}

// ---------------- bf16 MFMA GEMM: C = A[M][Kstride] @ BT[N][Kstride]^T ----------------
// EPI: 0 = bf16 store + bias; 1 = qkv head-major scatter + bias;
//      2 = exact gelu + bias, bf16 store; 3 = split-K fp32 partial store (no bias).
// K-range per block: [blockIdx.z*Ksl, (blockIdx.z+1)*Ksl)
template<int EPI>
__global__ __launch_bounds__(256) void gemm_kernel(const u16* __restrict__ A,
                                                   const u16* __restrict__ BT,
                                                   const float* __restrict__ bias,
                                                   void* __restrict__ out0v,
                                                   u16* __restrict__ out1, u16* __restrict__ out2,
                                                   int M, int N, int Kstride, int Ksl) {
    __shared__ u16 As[128 * 32];
    __shared__ u16 Bs[128 * 32];
    const int tid = threadIdx.x;
    const int lane = tid & 63;
    const int wave = tid >> 6;
    const int quad = lane >> 4;
    const int l15 = lane & 15;
    const int wy = wave >> 1, wx = wave & 1;
    const int m0 = blockIdx.y * 128;
    const int n0 = blockIdx.x * 128;
    const int koff = blockIdx.z * Ksl;

    const int ai0 = wave * 2, ai1 = wave * 2 + 1;
    const u16* aG0 = A + (size_t)(m0 + ai0 * 16 + (lane >> 2)) * Kstride + (lane & 3) * 8;
    const u16* aG1 = A + (size_t)(m0 + ai1 * 16 + (lane >> 2)) * Kstride + (lane & 3) * 8;
    const u16* bG0 = BT + (size_t)(n0 + ai0 * 16 + (lane >> 2)) * Kstride + (lane & 3) * 8;
    const u16* bG1 = BT + (size_t)(n0 + ai1 * 16 + (lane >> 2)) * Kstride + (lane & 3) * 8;
    u16* aL0 = &As[ai0 * 512];
    u16* aL1 = &As[ai1 * 512];
    u16* bL0 = &Bs[ai0 * 512];
    u16* bL1 = &Bs[ai1 * 512];

    f32x4 acc[4][4] = {};

    for (int k0 = koff; k0 < koff + Ksl; k0 += 32) {
        async_copy16(aG0 + k0, aL0);
        async_copy16(aG1 + k0, aL1);
        async_copy16(bG0 + k0, bL0);
        async_copy16(bG1 + k0, bL1);
        __syncthreads();
        s16x8 af[4], bf[4];
#pragma unroll
        for (int i = 0; i < 4; i++)
            af[i] = *(const s16x8*)&As[(wy * 64 + i * 16 + l15) * 32 + quad * 8];
#pragma unroll
        for (int j = 0; j < 4; j++)
            bf[j] = *(const s16x8*)&Bs[(wx * 64 + j * 16 + l15) * 32 + quad * 8];
#pragma unroll
        for (int i = 0; i < 4; i++)
#pragma unroll
            for (int j = 0; j < 4; j++)
                acc[i][j] = __builtin_amdgcn_mfma_f32_16x16x32_bf16(af[i], bf[j], acc[i][j], 0, 0, 0);
        __syncthreads();
    }

    const size_t MN = (size_t)M * N;
#pragma unroll
    for (int i = 0; i < 4; i++) {
#pragma unroll
        for (int j = 0; j < 4; j++) {
            f32x4 c = acc[i][j];
            int gn = n0 + wx * 64 + j * 16 + l15;
            float bv = (EPI == 3) ? 0.f : bias[gn];
#pragma unroll
            for (int r = 0; r < 4; r++) {
                int gm = m0 + wy * 64 + i * 16 + quad * 4 + r;
                float v = c[r] + bv;
                if (EPI == 2) v = 0.5f * v * (1.f + erff(v * 0.70710678118f));
                if (EPI == 0 || EPI == 2) {
                    ((u16*)out0v)[(size_t)gm * N + gn] = f2bf(v);
                } else if (EPI == 3) {
                    ((float*)out0v)[(size_t)blockIdx.z * MN + (size_t)gm * N + gn] = v;
                } else {
                    int which = gn >> 10, h = (gn >> 6) & 15, d = gn & 63;
                    int bb = gm >> 10, t = gm & 1023;
                    u16* dst = (which == 0) ? (u16*)out0v : ((which == 1) ? out1 : out2);
                    dst[((size_t)(bb * NH + h) * TT + t) * HD + d] = f2bf(v);
                }
            }
        }
    }
}

// ---------------- attention: 512 threads = 8 waves, each wave owns 128 keys ----------------
__global__ __launch_bounds__(512) void attn_kernel(const u16* __restrict__ Qb,
                                                   const u16* __restrict__ Kb,
                                                   const u16* __restrict__ VTb,
                                                   const float* __restrict__ rel_bias,
                                                   const float* __restrict__ temp_p,
                                                   float* __restrict__ probs_out,
                                                   u16* __restrict__ attn_out) {
    __shared__ __align__(16) u16 Qs[16 * 72];
    __shared__ __align__(16) u16 Ps[16 * 1032];   // reused as float Op[8][16][64] later
    __shared__ float red[2][8][16];
    __shared__ float RB[1040];

    const int tid = threadIdx.x;
    const int lane = tid & 63, wave = tid >> 6, quad = lane >> 4, l15 = lane & 15;
    const int q0 = blockIdx.x * 16;
    const int h = blockIdx.y, b = blockIdx.z;
    const int bh = b * NH + h;
    const size_t headoff = (size_t)bh * TT * HD;

    float temp = fmaxf(temp_p[0], 0.01f);
    const float itemp = 1.f / temp;

    // stage rel_bias slice: indices [1008-q0, 2046-q0] of this head's row
    for (int i = tid; i < 1039; i += 512)
        RB[i] = rel_bias[h * 2047 + (1008 - q0) + i];
    if (tid < 256) {  // 16x64 Q tile
        int row = tid >> 4, col = (tid & 15) * 4;
        const u16* srcp = Qb + headoff + (size_t)(q0 + row) * HD + col;
        *(uint2*)&Qs[row * 72 + col] = *(const uint2*)srcp;
    }
    __syncthreads();

    // ---- S = Q K^T * (1/temp) + rel_bias ----
    s16x8 a0 = *(const s16x8*)&Qs[l15 * 72 + quad * 8];
    s16x8 a1 = *(const s16x8*)&Qs[l15 * 72 + 32 + quad * 8];
    f32x4 s[8];
    const u16* Kh = Kb + headoff;
#pragma unroll
    for (int nt = 0; nt < 8; nt++) {
        int key = wave * 128 + nt * 16 + l15;
        const u16* kp = Kh + (size_t)key * HD;
        s16x8 b0 = *(const s16x8*)(kp + quad * 8);
        s16x8 b1 = *(const s16x8*)(kp + 32 + quad * 8);
        f32x4 acc = {};
        acc = __builtin_amdgcn_mfma_f32_16x16x32_bf16(a0, b0, acc, 0, 0, 0);
        acc = __builtin_amdgcn_mfma_f32_16x16x32_bf16(a1, b1, acc, 0, 0, 0);
#pragma unroll
        for (int r = 0; r < 4; r++)
            acc[r] = acc[r] * itemp + RB[key - (quad * 4 + r) + 15];
        s[nt] = acc;
    }

    // ---- row max ----
    float lm[4];
#pragma unroll
    for (int r = 0; r < 4; r++) {
        float m = s[0][r];
#pragma unroll
        for (int nt = 1; nt < 8; nt++) m = fmaxf(m, s[nt][r]);
        for (int off = 8; off >= 1; off >>= 1) m = fmaxf(m, __shfl_xor(m, off));
        lm[r] = m;
    }
    if (l15 == 0)
        for (int r = 0; r < 4; r++) red[0][wave][quad * 4 + r] = lm[r];
    __syncthreads();
    float rm[4];
#pragma unroll
    for (int r = 0; r < 4; r++) {
        int row = quad * 4 + r;
        float m = red[0][0][row];
#pragma unroll
        for (int w = 1; w < 8; w++) m = fmaxf(m, red[0][w][row]);
        rm[r] = m;
    }

    // ---- exp + row sum ----
    float ls[4] = {0.f, 0.f, 0.f, 0.f};
#pragma unroll
    for (int nt = 0; nt < 8; nt++)
#pragma unroll
        for (int r = 0; r < 4; r++) {
            float p = __expf(s[nt][r] - rm[r]);
            s[nt][r] = p;
            ls[r] += p;
        }
#pragma unroll
    for (int r = 0; r < 4; r++) {
        float v = ls[r];
        for (int off = 8; off >= 1; off >>= 1) v += __shfl_xor(v, off);
        ls[r] = v;
    }
    if (l15 == 0)
        for (int r = 0; r < 4; r++) red[1][wave][quad * 4 + r] = ls[r];
    __syncthreads();
    float inv[4];
#pragma unroll
    for (int r = 0; r < 4; r++) {
        int row = quad * 4 + r;
        float v = red[1][0][row];
#pragma unroll
        for (int w = 1; w < 8; w++) v += red[1][w][row];
        inv[r] = 1.f / v;
    }

    // ---- write normalized probs (fp32 to d_out) + normalized bf16 P into LDS ----
    float* prow = probs_out + ((size_t)bh * TT + q0) * TT;
#pragma unroll
    for (int nt = 0; nt < 8; nt++) {
        int key = wave * 128 + nt * 16 + l15;
#pragma unroll
        for (int r = 0; r < 4; r++) {
            int row = quad * 4 + r;
            float pn = s[nt][r] * inv[r];
            prow[(size_t)row * TT + key] = pn;
            Ps[row * 1032 + key] = f2bf(pn);
        }
    }
    __syncthreads();

    // ---- O = P V over this wave's 128-key slab ----
    f32x4 o[4] = {};
    const u16* Vh = VTb + headoff;
#pragma unroll
    for (int ks = 0; ks < 4; ks++) {
        int k0 = wave * 128 + ks * 32;
        s16x8 pa = *(const s16x8*)&Ps[l15 * 1032 + k0 + quad * 8];
#pragma unroll
        for (int nt = 0; nt < 4; nt++) {
            int d = nt * 16 + l15;
            s16x8 vb = *(const s16x8*)(Vh + (size_t)d * TT + k0 + quad * 8);
            o[nt] = __builtin_amdgcn_mfma_f32_16x16x32_bf16(pa, vb, o[nt], 0, 0, 0);
        }
    }
    __syncthreads();  // all waves done reading Ps
    float* OpF = (float*)Ps;  // [8][16][64]
#pragma unroll
    for (int nt = 0; nt < 4; nt++)
#pragma unroll
        for (int r = 0; r < 4; r++)
            OpF[(wave * 16 + quad * 4 + r) * 64 + nt * 16 + l15] = o[nt][r];
    __syncthreads();

    {
        int m = tid >> 5, dc = (tid & 31) * 2;
        float a0v = 0.f, a1v = 0.f;
#pragma unroll
        for (int w = 0; w < 8; w++) {
            a0v += OpF[(w * 16 + m) * 64 + dc];
            a1v += OpF[(w * 16 + m) * 64 + dc + 1];
        }
        u16 pk[2] = {f2bf(a0v), f2bf(a1v)};
        *(unsigned*)&attn_out[((size_t)(b * TT + q0 + m)) * DM + h * HD + dc] = *(unsigned*)pk;
    }
}

// ---------------- layernorm with fused split-K reduce + bias ----------------
// MODE 0: x = LN(src_f32 + (biasN + sum_kz part)) -> bf16         (LN1, KS=2)
// MODE 1: y = LN(x_bf + scale*(biasN + sum_kz part)) -> fp32      (LN2, KS=4)
template<int MODE, int KS>
__global__ __launch_bounds__(256) void ln_kernel(const float* __restrict__ af32,
                                                 const u16* __restrict__ abf,
                                                 const float* __restrict__ part,
                                                 const float* __restrict__ biasN,
                                                 const float* __restrict__ scale_p,
                                                 const float* __restrict__ gamma,
                                                 const float* __restrict__ beta,
                                                 float* __restrict__ outf,
                                                 u16* __restrict__ outbf) {
    __shared__ float red[2][4];
    const size_t MN = (size_t)BB * TT * DM;
    int row = blockIdx.x;
    int tid = threadIdx.x;
    float sc = (MODE == 1) ? scale_p[0] : 1.f;
    int c0 = tid * 4;
    size_t base = (size_t)row * DM + c0;
    float4 a = *(const float4*)(biasN + c0);
    float acc[4] = {a.x, a.y, a.z, a.w};
#pragma unroll
    for (int kz = 0; kz < KS; kz++) {
        float4 p = *(const float4*)(part + kz * MN + base);
        acc[0] += p.x; acc[1] += p.y; acc[2] += p.z; acc[3] += p.w;
    }
    float x[4];
#pragma unroll
    for (int c = 0; c < 4; c++) {
        float b0 = (MODE == 0) ? af32[base + c] : bf2f(abf[base + c]);
        x[c] = b0 + sc * acc[c];
    }
    float s = x[0] + x[1] + x[2] + x[3];
    float sq = x[0] * x[0] + x[1] * x[1] + x[2] * x[2] + x[3] * x[3];
    for (int off = 32; off >= 1; off >>= 1) {
        s += __shfl_xor(s, off);
        sq += __shfl_xor(sq, off);
    }
    int wave = tid >> 6;
    if ((tid & 63) == 0) {
        red[0][wave] = s;
        red[1][wave] = sq;
    }
    __syncthreads();
    s = red[0][0] + red[0][1] + red[0][2] + red[0][3];
    sq = red[1][0] + red[1][1] + red[1][2] + red[1][3];
    float mu = s * (1.f / DM);
    float var = sq * (1.f / DM) - mu * mu;
    float rs = rsqrtf(var + 1e-5f);
#pragma unroll
    for (int c = 0; c < 4; c++) {
        float y = (x[c] - mu) * rs * gamma[c0 + c] + beta[c0 + c];
        if (MODE == 0) outbf[base + c] = f2bf(y);
        else outf[base + c] = y;
    }
}

// ---------------- workspace layout (bytes) ----------------
#define OFF_SRCBF 0UL
#define OFF_WQKVT 8388608UL
#define OFF_WOT 14680064UL
#define OFF_W1T 16777216UL
#define OFF_W2T 25165824UL
#define OFF_Q 33554432UL
#define OFF_K 41943040UL
#define OFF_V 50331648UL
#define OFF_VT 58720256UL
#define OFF_ATTNO 67108864UL
#define OFF_XBF 83886080UL
#define OFF_H1 92274688UL
#define OFF_PART 134217728UL   // 4 x 16MB fp32 partials (reused proj->ff2)

extern "C" void kernel_launch(void* const* d_in, const int* in_sizes, int n_in,
                              void* d_out, int out_size, void* d_ws, size_t ws_size,
                              hipStream_t stream) {
    const float* src = (const float*)d_in[0];
    const float* Wqkv = (const float*)d_in[1];
    const float* bqkv = (const float*)d_in[2];
    const float* Wo = (const float*)d_in[3];
    const float* bo = (const float*)d_in[4];
    const float* relb = (const float*)d_in[5];
    const float* temp = (const float*)d_in[6];
    const float* W1 = (const float*)d_in[7];
    const float* b1 = (const float*)d_in[8];
    const float* W2 = (const float*)d_in[9];
    const float* b2 = (const float*)d_in[10];
    const float* ffs = (const float*)d_in[11];
    const float* g1 = (const float*)d_in[12];
    const float* be1 = (const float*)d_in[13];
    const float* g2 = (const float*)d_in[14];
    const float* be2 = (const float*)d_in[15];

    char* ws = (char*)d_ws;
    u16* srcbf = (u16*)(ws + OFF_SRCBF);
    u16* WqkvT = (u16*)(ws + OFF_WQKVT);
    u16* WoT = (u16*)(ws + OFF_WOT);
    u16* W1T = (u16*)(ws + OFF_W1T);
    u16* W2T = (u16*)(ws + OFF_W2T);
    u16* Qb = (u16*)(ws + OFF_Q);
    u16* Kb = (u16*)(ws + OFF_K);
    u16* Vb = (u16*)(ws + OFF_V);
    u16* VTb = (u16*)(ws + OFF_VT);
    u16* attnbf = (u16*)(ws + OFF_ATTNO);
    u16* xbf = (u16*)(ws + OFF_XBF);
    u16* h1bf = (u16*)(ws + OFF_H1);
    float* partF = (float*)(ws + OFF_PART);

    float* out_f = (float*)d_out;
    float* probs = out_f + (size_t)BB * TT * DM;

    // 1. src -> bf16
    cvt_kernel<<<4096, 256, 0, stream>>>(src, srcbf, BB * TT * DM);
    // 2-5. weight transposes (fp32 [K][N] -> bf16 [N][K])
    transpose_kernel<0><<<dim3(N3 / 32, DM / 32, 1), 256, 0, stream>>>(Wqkv, WqkvT, DM, N3);
    transpose_kernel<0><<<dim3(DM / 32, DM / 32, 1), 256, 0, stream>>>(Wo, WoT, DM, DM);
    transpose_kernel<0><<<dim3(DFF / 32, DM / 32, 1), 256, 0, stream>>>(W1, W1T, DM, DFF);
    transpose_kernel<0><<<dim3(DM / 32, DFF / 32, 1), 256, 0, stream>>>(W2, W2T, DFF, DM);
    // 6. QKV GEMM with head-major scatter
    gemm_kernel<1><<<dim3(N3 / 128, (BB * TT) / 128, 1), 256, 0, stream>>>(
        srcbf, WqkvT, bqkv, Qb, Kb, Vb, BB * TT, N3, DM, DM);
    // 7. V -> V^T per head
    transpose_kernel<1><<<dim3(HD / 32, TT / 32, BB * NH), 256, 0, stream>>>(Vb, VTb, TT, HD);
    // 8. attention (probs -> d_out, attn_out bf16)
    attn_kernel<<<dim3(TT / 16, NH, BB), 512, 0, stream>>>(Qb, Kb, VTb, relb, temp, probs, attnbf);
    // 9. output projection, split-K=2 -> fp32 partials
    gemm_kernel<3><<<dim3(DM / 128, (BB * TT) / 128, 2), 256, 0, stream>>>(
        attnbf, WoT, nullptr, partF, nullptr, nullptr, BB * TT, DM, DM, DM / 2);
    // 10. LN1: x = LN(src + bo + sum(part))
    ln_kernel<0, 2><<<BB * TT, 256, 0, stream>>>(src, nullptr, partF, bo, nullptr, g1, be1,
                                                 nullptr, xbf);
    // 11. FF1 + exact gelu
    gemm_kernel<2><<<dim3(DFF / 128, (BB * TT) / 128, 1), 256, 0, stream>>>(
        xbf, W1T, b1, h1bf, nullptr, nullptr, BB * TT, DFF, DM, DM);
    // 12. FF2, split-K=4 -> fp32 partials
    gemm_kernel<3><<<dim3(DM / 128, (BB * TT) / 128, 4), 256, 0, stream>>>(
        h1bf, W2T, nullptr, partF, nullptr, nullptr, BB * TT, DM, DFF, DFF / 4);
    // 13. LN2 -> d_out
    ln_kernel<1, 4><<<BB * TT, 256, 0, stream>>>(nullptr, xbf, partF, b2, ffs, g2, be2,
                                                 out_f, nullptr);
}